// Round 6
// baseline (28697.314 us; speedup 1.0000x reference)
//
#include <hip/hip_runtime.h>
#include <stdint.h>

typedef __attribute__((ext_vector_type(4))) float f32x4;
typedef __attribute__((ext_vector_type(8))) short s16x8;
typedef unsigned short ushort_t;

#define DEVINL static __device__ __forceinline__

DEVINL ushort_t f2bf(float f) {
  unsigned int u = __float_as_uint(f);
  u += 0x7FFFu + ((u >> 16) & 1u);            // RNE
  return (ushort_t)(u >> 16);
}
DEVINL float bf2f(ushort_t h) {
  return __uint_as_float(((unsigned int)h) << 16);
}
DEVINL void split2(float v, ushort_t& hi, ushort_t& lo) {
  hi = f2bf(v);
  lo = f2bf(v - bf2f(hi));                    // combined rel err ~2^-17
}
DEVINL float sigf(float x)   { return 1.f / (1.f + __expf(-x)); }
DEVINL float tanhf_(float x) { return 1.f - 2.f / (__expf(2.f * x) + 1.f); }  // stable both tails

// ---------------- prep: reorder rows into G = hcol*4 + gate; split w_hh ----------------
__global__ __launch_bounds__(256) void k_prep(
    const float* __restrict__ wih,   // [4096][512]  rows: gate*1024 + hcol
    const float* __restrict__ whh,   // [4096][1024]
    const float* __restrict__ b,     // [4096]
    float* __restrict__ wihR,        // [4096][512]  rows: hcol*4 + gate
    float* __restrict__ biasR,       // [4096]
    ushort_t* __restrict__ whhR_hi,  // [4096][1024]
    ushort_t* __restrict__ whhR_lo)
{
  int hcol = blockIdx.x;             // 0..1023
  int tid = threadIdx.x;
  for (int g = 0; g < 4; ++g) {
    int G = hcol * 4 + g;
    int orig = g * 1024 + hcol;
    const float* src_ih = wih + (size_t)orig * 512;
    float* dst_ih = wihR + (size_t)G * 512;
    dst_ih[tid] = src_ih[tid];
    dst_ih[tid + 256] = src_ih[tid + 256];
    const float* src_hh = whh + (size_t)orig * 1024;
    ushort_t* dh = whhR_hi + (size_t)G * 1024;
    ushort_t* dl = whhR_lo + (size_t)G * 1024;
#pragma unroll
    for (int r = 0; r < 4; ++r) {
      int j = tid + r * 256;
      ushort_t h_, l_;
      split2(src_hh[j], h_, l_);
      dh[j] = h_; dl[j] = l_;
    }
    if (tid == 0) biasR[G] = b[orig];
  }
}

// ---------------- xproj split-bf16 GEMM (one T-chunk of 128) ----------------
__global__ __launch_bounds__(256) void k_gemm_chunk(
    const float* __restrict__ x,     // [64][1024][512]
    const float* __restrict__ wihR,  // [4096][512] (G-ordered rows)
    const float* __restrict__ biasR, // [4096]
    float* __restrict__ xp,          // [128][64][4096]
    int chunk)
{
  __shared__ __align__(16) ushort_t Ah[128 * 64], Al[128 * 64];
  __shared__ __align__(16) ushort_t Bh[128 * 64], Bl[128 * 64];
  const int K = 512;
  int bid = blockIdx.x;
  int ntile = bid & 31, mtile = bid >> 5;
  int m0 = mtile * 128, n0 = ntile * 128;
  int tid = threadIdx.x, lane = tid & 63, wv = tid >> 6;
  int wm = wv >> 1, wn = wv & 1;
  int lm = lane & 15, lk = lane >> 4;
  int sr = tid >> 3;
  int sc = (tid & 7) * 8;

  f32x4 acc[4][4] = {};
  float ax[4][8], bx[4][8];

#pragma unroll
  for (int p = 0; p < 4; ++p) {
    int am = m0 + p * 32 + sr;
    const float* ap = x + (size_t)((am >> 7) * 1024 + chunk * 128 + (am & 127)) * K + sc;
    const float* bp = wihR + (size_t)(n0 + p * 32 + sr) * K + sc;
#pragma unroll
    for (int e = 0; e < 8; ++e) ax[p][e] = ap[e];
#pragma unroll
    for (int e = 0; e < 8; ++e) bx[p][e] = bp[e];
  }

  for (int k0 = 0; k0 < K; k0 += 64) {
    __syncthreads();
#pragma unroll
    for (int p = 0; p < 4; ++p) {
      s16x8 vah, val, vbh, vbl;
#pragma unroll
      for (int e = 0; e < 8; ++e) {
        ushort_t h_, l_;
        split2(ax[p][e], h_, l_); vah[e] = (short)h_; val[e] = (short)l_;
        split2(bx[p][e], h_, l_); vbh[e] = (short)h_; vbl[e] = (short)l_;
      }
      int rw = p * 32 + sr;
      int wb = (rw * 128 + sc * 2) ^ ((rw & 7) << 4);
      *(s16x8*)((char*)Ah + wb) = vah;
      *(s16x8*)((char*)Al + wb) = val;
      *(s16x8*)((char*)Bh + wb) = vbh;
      *(s16x8*)((char*)Bl + wb) = vbl;
    }
    __syncthreads();
    if (k0 + 64 < K) {
#pragma unroll
      for (int p = 0; p < 4; ++p) {
        int am = m0 + p * 32 + sr;
        const float* ap = x + (size_t)((am >> 7) * 1024 + chunk * 128 + (am & 127)) * K + (k0 + 64) + sc;
        const float* bp = wihR + (size_t)(n0 + p * 32 + sr) * K + (k0 + 64) + sc;
#pragma unroll
        for (int e = 0; e < 8; ++e) ax[p][e] = ap[e];
#pragma unroll
        for (int e = 0; e < 8; ++e) bx[p][e] = bp[e];
      }
    }
#pragma unroll
    for (int kk = 0; kk < 2; ++kk) {
      s16x8 fah[4], fal[4], fbh[4], fbl[4];
      int cb = (kk * 32 + lk * 8) * 2;
#pragma unroll
      for (int i = 0; i < 4; ++i) {
        int rA = wm * 64 + i * 16 + lm;
        int rB = wn * 64 + i * 16 + lm;
        int oa = (rA * 128 + cb) ^ ((rA & 7) << 4);
        int ob = (rB * 128 + cb) ^ ((rB & 7) << 4);
        fah[i] = *(const s16x8*)((const char*)Ah + oa);
        fal[i] = *(const s16x8*)((const char*)Al + oa);
        fbh[i] = *(const s16x8*)((const char*)Bh + ob);
        fbl[i] = *(const s16x8*)((const char*)Bl + ob);
      }
#pragma unroll
      for (int i = 0; i < 4; ++i)
#pragma unroll
        for (int j = 0; j < 4; ++j) {
          acc[i][j] = __builtin_amdgcn_mfma_f32_16x16x32_bf16(fah[i], fbh[j], acc[i][j], 0, 0, 0);
          acc[i][j] = __builtin_amdgcn_mfma_f32_16x16x32_bf16(fah[i], fbl[j], acc[i][j], 0, 0, 0);
          acc[i][j] = __builtin_amdgcn_mfma_f32_16x16x32_bf16(fal[i], fbh[j], acc[i][j], 0, 0, 0);
        }
    }
  }
#pragma unroll
  for (int j = 0; j < 4; ++j) {
    int G = n0 + wn * 64 + j * 16 + lm;
    float bv = biasR[G];
#pragma unroll
    for (int i = 0; i < 4; ++i) {
      int mb = m0 + wm * 64 + i * 16 + lk * 4;
#pragma unroll
      for (int r = 0; r < 4; ++r) {
        int m = mb + r;
        xp[((size_t)(m & 127) * 64 + (m >> 7)) * 4096 + G] = acc[i][j][r] + bv;
      }
    }
  }
}

// ---------------- persistent LSTM recurrence, one T-chunk of 128 steps ----------------
// 256 WGs x 512 thr (forced 1 WG/CU via LDS padding). Group g = bid>>6 owns batches
// [16g,16g+16); WG w = bid&63 owns G-cols [64w,64w+64) = hcols [16w,16w+16).
// Wave wid: kh = wid&1 (K-half), cg = wid>>1 (16-col group). w_hh hi/lo frags in VGPRs
// (128/wave). h exchanged via per-group global planes [16][1024] hi/lo, double-buffered.
// Spin barrier with bailout cap (wrong-answer-not-hang safety).
__global__ __launch_bounds__(512, 1) void k_lstm_chunk(
    const float* __restrict__ xp,          // [128][64][4096]
    const ushort_t* __restrict__ whh_hi,   // [4096][1024]
    const ushort_t* __restrict__ whh_lo,
    ushort_t* __restrict__ h0hi, ushort_t* __restrict__ h0lo,  // [4][16][1024]
    ushort_t* __restrict__ h1hi, ushort_t* __restrict__ h1lo,
    unsigned int* __restrict__ arrived,    // [4][64]
    float* __restrict__ c_ws,              // [64][1024]
    int chunk)
{
  __shared__ __align__(16) ushort_t hA[16 * 1024];   // hi plane, swizzled
  __shared__ __align__(16) ushort_t hB[16 * 1024];   // lo plane, swizzled
  __shared__ float g0[4][16][17], g1[4][16][17];
  __shared__ float pad_force[2112];                   // force 1 WG/CU (>80KB total)

  int bid = blockIdx.x;
  int g = bid >> 6, w = bid & 63;
  int tid = threadIdx.x, lane = tid & 63, wid = tid >> 6;
  int kh = wid & 1, cg = wid >> 1;
  int lm = lane & 15, lk = lane >> 4;
  if ((uintptr_t)xp == 1) pad_force[tid] = 1.f;      // opaque: keeps LDS pad allocated

  // --- load this wave's w_hh hi/lo B-frags into VGPRs (once per chunk) ---
  s16x8 bh[16], bl[16];
  {
    int gcol = w * 64 + cg * 16 + lm;
    const ushort_t* ph = whh_hi + (size_t)gcol * 1024 + kh * 512 + lk * 8;
    const ushort_t* pl = whh_lo + (size_t)gcol * 1024 + kh * 512 + lk * 8;
#pragma unroll
    for (int kk = 0; kk < 16; ++kk) {
      bh[kk] = *(const s16x8*)(ph + kk * 32);
      bl[kk] = *(const s16x8*)(pl + kk * 32);
    }
  }

  // cell ownership (tid < 256): bat = tid>>4, hc = tid&15
  int bat = tid >> 4, hc = tid & 15;
  int gbat = g * 16 + bat;
  int hcol = w * 16 + hc;
  float c_st = (tid < 256) ? c_ws[(size_t)gbat * 1024 + hcol] : 0.f;

  unsigned int* grp = arrived + g * 64;
  int gbase = g * 16384;

  for (int tl = 0; tl < 128; ++tl) {
    const ushort_t* shi = (tl & 1) ? h1hi : h0hi;
    const ushort_t* slo = (tl & 1) ? h1lo : h0lo;
    ushort_t* dhi = (tl & 1) ? h0hi : h1hi;
    ushort_t* dlo = (tl & 1) ? h0lo : h1lo;

    // stage group's h hi/lo (32KB each) into LDS with XOR swizzle
    {
      const s16x8* sh = (const s16x8*)(shi + gbase);
      const s16x8* sl = (const s16x8*)(slo + gbase);
#pragma unroll
      for (int i = 0; i < 4; ++i) {
        int idx = tid + 512 * i;                 // 16B chunk index (2048 per plane)
        int byte = idx * 16;
        int dst = byte ^ (((byte >> 11) & 7) << 4);
        *(s16x8*)((char*)hA + dst) = sh[idx];
        *(s16x8*)((char*)hB + dst) = sl[idx];
      }
    }
    __syncthreads();

    // split GEMM, this wave: A rows = 16 bats, B = its 16 G-cols, K-half kh
    f32x4 acc = {};
#pragma unroll
    for (int kk = 0; kk < 16; ++kk) {
      int kb = (kh * 512 + kk * 32 + lk * 8) * 2;
      int off = (lm * 2048 + kb) ^ ((lm & 7) << 4);
      s16x8 ah = *(const s16x8*)((const char*)hA + off);
      s16x8 al = *(const s16x8*)((const char*)hB + off);
      acc = __builtin_amdgcn_mfma_f32_16x16x32_bf16(ah, bh[kk], acc, 0, 0, 0);
      acc = __builtin_amdgcn_mfma_f32_16x16x32_bf16(al, bh[kk], acc, 0, 0, 0);
      acc = __builtin_amdgcn_mfma_f32_16x16x32_bf16(ah, bl[kk], acc, 0, 0, 0);
    }
    {
      float (*gp)[16][17] = kh ? g1 : g0;
#pragma unroll
      for (int r = 0; r < 4; ++r)
        gp[cg][lk * 4 + r][lm] = acc[r];
    }
    __syncthreads();

    // elementwise cell update (tid < 256)
    if (tid < 256) {
      f32x4 xv = *(const f32x4*)(xp + ((size_t)tl * 64 + gbat) * 4096 + w * 64 + hc * 4);
      int cgi = hc >> 2, nb = (hc & 3) * 4;
      float gi = g0[cgi][bat][nb + 0] + g1[cgi][bat][nb + 0] + xv[0];
      float gf = g0[cgi][bat][nb + 1] + g1[cgi][bat][nb + 1] + xv[1];
      float gg = g0[cgi][bat][nb + 2] + g1[cgi][bat][nb + 2] + xv[2];
      float go = g0[cgi][bat][nb + 3] + g1[cgi][bat][nb + 3] + xv[3];
      float iv = sigf(gi), fv = sigf(gf), gv = tanhf_(gg), ov = sigf(go);
      c_st = fv * c_st + iv * gv;
      float hv = ov * tanhf_(c_st);
      ushort_t h_, l_;
      split2(hv, h_, l_);
      dhi[gbase + bat * 1024 + hcol] = h_;
      dlo[gbase + bat * 1024 + hcol] = l_;
    }

    // group barrier: stores -> L2 (sync drains vmcnt) -> wbl2 -> flag -> poll -> inv
    __syncthreads();
    unsigned int tgt = (unsigned int)(chunk * 128 + tl + 1);
    if (tid == 0) {
      __builtin_amdgcn_fence(__ATOMIC_RELEASE, "agent");
      __hip_atomic_store(grp + w, tgt, __ATOMIC_RELAXED, __HIP_MEMORY_SCOPE_AGENT);
    }
    if (tid < 64) {
      int spin = 0;
      while (1) {
        unsigned int v = __hip_atomic_load(grp + lane, __ATOMIC_RELAXED, __HIP_MEMORY_SCOPE_AGENT);
        if (__all((int)(v >= tgt))) break;
        if (++spin > (1 << 16)) break;          // bailout: wrong answer, never a hang
        __builtin_amdgcn_s_sleep(1);
      }
    }
    __syncthreads();
    __builtin_amdgcn_fence(__ATOMIC_ACQUIRE, "agent");
  }

  if (tid < 256) c_ws[(size_t)gbat * 1024 + hcol] = c_st;   // persist c for next chunk
}

// ---------------- final linear ----------------
__global__ __launch_bounds__(256) void k_final(
    const ushort_t* __restrict__ h_hi,  // [64][1024]
    const ushort_t* __restrict__ h_lo,
    const float* __restrict__ wlin,     // [512][1024]
    const float* __restrict__ blin,     // [512]
    float* __restrict__ out)            // [32768] = mu | logvar
{
  __shared__ float hrow[1024];
  int bat = blockIdx.x;
  int tid = threadIdx.x;
  for (int j = tid; j < 1024; j += 256)
    hrow[j] = bf2f(h_hi[(size_t)bat * 1024 + j]) + bf2f(h_lo[(size_t)bat * 1024 + j]);
  __syncthreads();
#pragma unroll
  for (int rep = 0; rep < 2; ++rep) {
    int col = tid + rep * 256;
    const float* wl = wlin + (size_t)col * 1024;
    float sum = 0.f;
    for (int k = 0; k < 1024; k += 4) {
      f32x4 wv = *(const f32x4*)(wl + k);
      sum += hrow[k] * wv[0] + hrow[k + 1] * wv[1] + hrow[k + 2] * wv[2] + hrow[k + 3] * wv[3];
    }
    sum += blin[col];
    if (col < 256) out[(size_t)bat * 256 + col] = sum;
    else           out[16384 + (size_t)bat * 256 + (col - 256)] = sum;
  }
}

// ---------------- launcher ----------------
extern "C" void kernel_launch(void* const* d_in, const int* in_sizes, int n_in,
                              void* d_out, int out_size, void* d_ws, size_t ws_size,
                              hipStream_t stream) {
  const float* x     = (const float*)d_in[0];
  const float* w_ih  = (const float*)d_in[1];
  const float* w_hh  = (const float*)d_in[2];
  const float* b     = (const float*)d_in[3];
  const float* w_lin = (const float*)d_in[4];
  const float* b_lin = (const float*)d_in[5];
  float* out = (float*)d_out;

  char* ws = (char*)d_ws;
  float*    xp      = (float*)ws;                           // 134,217,728
  float*    wihR    = (float*)(ws + 134217728LL);           //   8,388,608
  float*    biasR   = (float*)(ws + 142606336LL);           //      16,384
  ushort_t* whhR_hi = (ushort_t*)(ws + 142622720LL);        //   8,388,608
  ushort_t* whhR_lo = (ushort_t*)(ws + 151011328LL);        //   8,388,608
  float*    c_ws    = (float*)(ws + 159399936LL);           //     262,144
  ushort_t* h0hi    = (ushort_t*)(ws + 159662080LL);        //     131,072
  ushort_t* h0lo    = (ushort_t*)(ws + 159793152LL);        //     131,072
  unsigned int* arr = (unsigned int*)(ws + 159924224LL);    //       1,024 (pad 4,096)
  ushort_t* h1hi    = (ushort_t*)(ws + 159928320LL);        //     131,072
  ushort_t* h1lo    = (ushort_t*)(ws + 160059392LL);        //     131,072
  // total: 160,190,464 B

  if (ws_size < 160190464ULL) return;  // failure signature: absmax == max|ref| ~ 0.305

  // zero c, h buffer 0, barrier counters (contiguous region)
  (void)hipMemsetAsync(ws + 159399936LL, 0, 262144 + 131072 + 131072 + 4096, stream);

  k_prep<<<1024, 256, 0, stream>>>(w_ih, w_hh, b, wihR, biasR, whhR_hi, whhR_lo);

  for (int c = 0; c < 8; ++c) {
    k_gemm_chunk<<<2048, 256, 0, stream>>>(x, wihR, biasR, xp, c);
    k_lstm_chunk<<<256, 512, 0, stream>>>(xp, whhR_hi, whhR_lo,
                                          h0hi, h0lo, h1hi, h1lo, arr, c_ws, c);
  }
  // each chunk runs 128 steps (even) -> h_final ends in buffer 0
  k_final<<<64, 256, 0, stream>>>(h0hi, h0lo, w_lin, b_lin, out);
}

// Round 7
// 9526.936 us; speedup vs baseline: 3.0122x; 3.0122x over previous
//
#include <hip/hip_runtime.h>
#include <stdint.h>

typedef __attribute__((ext_vector_type(4))) float f32x4;
typedef __attribute__((ext_vector_type(8))) short s16x8;
typedef unsigned short ushort_t;

#define DEVINL static __device__ __forceinline__

DEVINL ushort_t f2bf(float f) {
  unsigned int u = __float_as_uint(f);
  u += 0x7FFFu + ((u >> 16) & 1u);            // RNE
  return (ushort_t)(u >> 16);
}
DEVINL float bf2f(ushort_t h) {
  return __uint_as_float(((unsigned int)h) << 16);
}
DEVINL void split2(float v, ushort_t& hi, ushort_t& lo) {
  hi = f2bf(v);
  lo = f2bf(v - bf2f(hi));                    // combined rel err ~2^-17
}
DEVINL float sigf(float x)   { return 1.f / (1.f + __expf(-x)); }
DEVINL float tanhf_(float x) { return 1.f - 2.f / (__expf(2.f * x) + 1.f); }  // stable both tails

// ---------------- prep: reorder rows into G = hcol*4 + gate; split w_hh ----------------
__global__ __launch_bounds__(256) void k_prep(
    const float* __restrict__ wih,   // [4096][512]  rows: gate*1024 + hcol
    const float* __restrict__ whh,   // [4096][1024]
    const float* __restrict__ b,     // [4096]
    float* __restrict__ wihR,        // [4096][512]  rows: hcol*4 + gate
    float* __restrict__ biasR,       // [4096]
    ushort_t* __restrict__ whhR_hi,  // [4096][1024]
    ushort_t* __restrict__ whhR_lo)
{
  int hcol = blockIdx.x;             // 0..1023
  int tid = threadIdx.x;
  for (int g = 0; g < 4; ++g) {
    int G = hcol * 4 + g;
    int orig = g * 1024 + hcol;
    const float* src_ih = wih + (size_t)orig * 512;
    float* dst_ih = wihR + (size_t)G * 512;
    dst_ih[tid] = src_ih[tid];
    dst_ih[tid + 256] = src_ih[tid + 256];
    const float* src_hh = whh + (size_t)orig * 1024;
    ushort_t* dh = whhR_hi + (size_t)G * 1024;
    ushort_t* dl = whhR_lo + (size_t)G * 1024;
#pragma unroll
    for (int r = 0; r < 4; ++r) {
      int j = tid + r * 256;
      ushort_t h_, l_;
      split2(src_hh[j], h_, l_);
      dh[j] = h_; dl[j] = l_;
    }
    if (tid == 0) biasR[G] = b[orig];
  }
}

// ---------------- xproj split-bf16 GEMM (one T-chunk of 128) ----------------
__global__ __launch_bounds__(256) void k_gemm_chunk(
    const float* __restrict__ x,     // [64][1024][512]
    const float* __restrict__ wihR,  // [4096][512] (G-ordered rows)
    const float* __restrict__ biasR, // [4096]
    float* __restrict__ xp,          // [128][64][4096]
    int chunk)
{
  __shared__ __align__(16) ushort_t Ah[128 * 64], Al[128 * 64];
  __shared__ __align__(16) ushort_t Bh[128 * 64], Bl[128 * 64];
  const int K = 512;
  int bid = blockIdx.x;
  int ntile = bid & 31, mtile = bid >> 5;
  int m0 = mtile * 128, n0 = ntile * 128;
  int tid = threadIdx.x, lane = tid & 63, wv = tid >> 6;
  int wm = wv >> 1, wn = wv & 1;
  int lm = lane & 15, lk = lane >> 4;
  int sr = tid >> 3;
  int sc = (tid & 7) * 8;

  f32x4 acc[4][4] = {};
  float ax[4][8], bx[4][8];

#pragma unroll
  for (int p = 0; p < 4; ++p) {
    int am = m0 + p * 32 + sr;
    const float* ap = x + (size_t)((am >> 7) * 1024 + chunk * 128 + (am & 127)) * K + sc;
    const float* bp = wihR + (size_t)(n0 + p * 32 + sr) * K + sc;
#pragma unroll
    for (int e = 0; e < 8; ++e) ax[p][e] = ap[e];
#pragma unroll
    for (int e = 0; e < 8; ++e) bx[p][e] = bp[e];
  }

  for (int k0 = 0; k0 < K; k0 += 64) {
    __syncthreads();
#pragma unroll
    for (int p = 0; p < 4; ++p) {
      s16x8 vah, val, vbh, vbl;
#pragma unroll
      for (int e = 0; e < 8; ++e) {
        ushort_t h_, l_;
        split2(ax[p][e], h_, l_); vah[e] = (short)h_; val[e] = (short)l_;
        split2(bx[p][e], h_, l_); vbh[e] = (short)h_; vbl[e] = (short)l_;
      }
      int rw = p * 32 + sr;
      int wb = (rw * 128 + sc * 2) ^ ((rw & 7) << 4);
      *(s16x8*)((char*)Ah + wb) = vah;
      *(s16x8*)((char*)Al + wb) = val;
      *(s16x8*)((char*)Bh + wb) = vbh;
      *(s16x8*)((char*)Bl + wb) = vbl;
    }
    __syncthreads();
    if (k0 + 64 < K) {
#pragma unroll
      for (int p = 0; p < 4; ++p) {
        int am = m0 + p * 32 + sr;
        const float* ap = x + (size_t)((am >> 7) * 1024 + chunk * 128 + (am & 127)) * K + (k0 + 64) + sc;
        const float* bp = wihR + (size_t)(n0 + p * 32 + sr) * K + (k0 + 64) + sc;
#pragma unroll
        for (int e = 0; e < 8; ++e) ax[p][e] = ap[e];
#pragma unroll
        for (int e = 0; e < 8; ++e) bx[p][e] = bp[e];
      }
    }
#pragma unroll
    for (int kk = 0; kk < 2; ++kk) {
      s16x8 fah[4], fal[4], fbh[4], fbl[4];
      int cb = (kk * 32 + lk * 8) * 2;
#pragma unroll
      for (int i = 0; i < 4; ++i) {
        int rA = wm * 64 + i * 16 + lm;
        int rB = wn * 64 + i * 16 + lm;
        int oa = (rA * 128 + cb) ^ ((rA & 7) << 4);
        int ob = (rB * 128 + cb) ^ ((rB & 7) << 4);
        fah[i] = *(const s16x8*)((const char*)Ah + oa);
        fal[i] = *(const s16x8*)((const char*)Al + oa);
        fbh[i] = *(const s16x8*)((const char*)Bh + ob);
        fbl[i] = *(const s16x8*)((const char*)Bl + ob);
      }
#pragma unroll
      for (int i = 0; i < 4; ++i)
#pragma unroll
        for (int j = 0; j < 4; ++j) {
          acc[i][j] = __builtin_amdgcn_mfma_f32_16x16x32_bf16(fah[i], fbh[j], acc[i][j], 0, 0, 0);
          acc[i][j] = __builtin_amdgcn_mfma_f32_16x16x32_bf16(fah[i], fbl[j], acc[i][j], 0, 0, 0);
          acc[i][j] = __builtin_amdgcn_mfma_f32_16x16x32_bf16(fal[i], fbh[j], acc[i][j], 0, 0, 0);
        }
    }
  }
#pragma unroll
  for (int j = 0; j < 4; ++j) {
    int G = n0 + wn * 64 + j * 16 + lm;
    float bv = biasR[G];
#pragma unroll
    for (int i = 0; i < 4; ++i) {
      int mb = m0 + wm * 64 + i * 16 + lk * 4;
#pragma unroll
      for (int r = 0; r < 4; ++r) {
        int m = mb + r;
        xp[((size_t)(m & 127) * 64 + (m >> 7)) * 4096 + G] = acc[i][j][r] + bv;
      }
    }
  }
}

// ---------------- persistent LSTM recurrence, one T-chunk of 128 steps ----------------
// 256 WGs x 512 thr (grid <= #CUs: co-residency guaranteed at any occupancy).
// Group g = bid>>6 owns batches [16g,16g+16); WG w = bid&63 owns hcols [16w,16w+16).
// h exchanged as packed u32 (hi<<16|lo) via RELAXED AGENT-SCOPE ATOMICS (sc0 sc1 bypass
// to LLC): no stale L1/L2 copies possible -> NO wbl2/inv fences anywhere in the loop.
__global__ __launch_bounds__(512, 1) void k_lstm_chunk(
    const float* __restrict__ xp,          // [128][64][4096]
    const ushort_t* __restrict__ whh_hi,   // [4096][1024]
    const ushort_t* __restrict__ whh_lo,
    unsigned int* __restrict__ hp0,        // [4][16][1024] packed h (hi<<16|lo)
    unsigned int* __restrict__ hp1,
    unsigned int* __restrict__ arrived,    // [4][64]
    float* __restrict__ c_ws,              // [64][1024]
    int chunk)
{
  __shared__ __align__(16) ushort_t hA[16 * 1024];   // hi plane, swizzled
  __shared__ __align__(16) ushort_t hB[16 * 1024];   // lo plane, swizzled
  __shared__ float g0[4][16][17], g1[4][16][17];

  int bid = blockIdx.x;
  int g = bid >> 6, w = bid & 63;
  int tid = threadIdx.x, lane = tid & 63, wid = tid >> 6;
  int kh = wid & 1, cg = wid >> 1;
  int lm = lane & 15, lk = lane >> 4;

  // --- this wave's w_hh hi/lo B-frags in VGPRs (once per chunk) ---
  s16x8 bh[16], bl[16];
  {
    int gcol = w * 64 + cg * 16 + lm;
    const ushort_t* ph = whh_hi + (size_t)gcol * 1024 + kh * 512 + lk * 8;
    const ushort_t* pl = whh_lo + (size_t)gcol * 1024 + kh * 512 + lk * 8;
#pragma unroll
    for (int kk = 0; kk < 16; ++kk) {
      bh[kk] = *(const s16x8*)(ph + kk * 32);
      bl[kk] = *(const s16x8*)(pl + kk * 32);
    }
  }

  // cell ownership (tid < 256): bat = tid>>4, hc = tid&15
  int bat = tid >> 4, hc = tid & 15;
  int gbat = g * 16 + bat;
  int hcol = w * 16 + hc;
  float c_st = (tid < 256) ? c_ws[(size_t)gbat * 1024 + hcol] : 0.f;

  unsigned int* grp = arrived + g * 64;
  unsigned int* hp0g = hp0 + g * 16384;
  unsigned int* hp1g = hp1 + g * 16384;

  for (int tl = 0; tl < 128; ++tl) {
    const unsigned long long* s64 =
        (const unsigned long long*)((tl & 1) ? hp1g : hp0g);
    unsigned int* dstp = (tl & 1) ? hp0g : hp1g;

    // xp prefetch: off the post-barrier critical path
    f32x4 xv = {};
    if (tid < 256)
      xv = *(const f32x4*)(xp + ((size_t)tl * 64 + gbat) * 4096 + w * 64 + hc * 4);

    // stage group's packed h (64KB) from LLC into swizzled hi/lo LDS planes
#pragma unroll
    for (int i = 0; i < 16; ++i) {
      int idx = tid + 512 * i;                       // u64 idx, 0..8191 (cells 2idx,2idx+1)
      unsigned long long xq =
          __hip_atomic_load(s64 + idx, __ATOMIC_RELAXED, __HIP_MEMORY_SCOPE_AGENT);
      unsigned int lo32 = (unsigned int)xq, hi32 = (unsigned int)(xq >> 32);
      unsigned int hiP = __builtin_amdgcn_perm(hi32, lo32, 0x07060302u);  // [hi_j, hi_j1]
      unsigned int loP = __builtin_amdgcn_perm(hi32, lo32, 0x05040100u);  // [lo_j, lo_j1]
      int byte = idx * 4;
      int dst = byte ^ (((byte >> 11) & 7) << 4);    // row(bat)-XOR swizzle
      *(unsigned int*)((char*)hA + dst) = hiP;
      *(unsigned int*)((char*)hB + dst) = loP;
    }
    __syncthreads();

    // split GEMM, this wave: 16 bats x its 16 G-cols, K-half kh
    f32x4 acc = {};
#pragma unroll
    for (int kk = 0; kk < 16; ++kk) {
      int kb = (kh * 512 + kk * 32 + lk * 8) * 2;
      int off = (lm * 2048 + kb) ^ ((lm & 7) << 4);
      s16x8 ah = *(const s16x8*)((const char*)hA + off);
      s16x8 al = *(const s16x8*)((const char*)hB + off);
      acc = __builtin_amdgcn_mfma_f32_16x16x32_bf16(ah, bh[kk], acc, 0, 0, 0);
      acc = __builtin_amdgcn_mfma_f32_16x16x32_bf16(al, bh[kk], acc, 0, 0, 0);
      acc = __builtin_amdgcn_mfma_f32_16x16x32_bf16(ah, bl[kk], acc, 0, 0, 0);
    }
    {
      float (*gp)[16][17] = kh ? g1 : g0;
#pragma unroll
      for (int r = 0; r < 4; ++r)
        gp[cg][lk * 4 + r][lm] = acc[r];
    }
    __syncthreads();

    // elementwise cell update; h published via bypass atomic store (LLC)
    if (tid < 256) {
      int cgi = hc >> 2, nb = (hc & 3) * 4;
      float gi = g0[cgi][bat][nb + 0] + g1[cgi][bat][nb + 0] + xv[0];
      float gf = g0[cgi][bat][nb + 1] + g1[cgi][bat][nb + 1] + xv[1];
      float gg = g0[cgi][bat][nb + 2] + g1[cgi][bat][nb + 2] + xv[2];
      float go = g0[cgi][bat][nb + 3] + g1[cgi][bat][nb + 3] + xv[3];
      float iv = sigf(gi), fv = sigf(gf), gv = tanhf_(gg), ov = sigf(go);
      c_st = fv * c_st + iv * gv;
      float hv = ov * tanhf_(c_st);
      ushort_t h_, l_;
      split2(hv, h_, l_);
      unsigned int pk = ((unsigned int)h_ << 16) | (unsigned int)l_;
      __hip_atomic_store(dstp + bat * 1024 + hcol, pk,
                         __ATOMIC_RELAXED, __HIP_MEMORY_SCOPE_AGENT);
    }

    // group barrier: __syncthreads drains each wave's vmcnt (stores at LLC) -> flag -> poll
    __syncthreads();
    unsigned int tgt = (unsigned int)(chunk * 128 + tl + 1);
    if (tid == 0)
      __hip_atomic_store(grp + w, tgt, __ATOMIC_RELAXED, __HIP_MEMORY_SCOPE_AGENT);
    if (tid < 64) {
      int spin = 0;
      while (1) {
        unsigned int v = __hip_atomic_load(grp + lane, __ATOMIC_RELAXED, __HIP_MEMORY_SCOPE_AGENT);
        if (__all((int)(v >= tgt))) break;
        if (++spin > (1 << 16)) break;          // bailout: wrong answer, never a hang
        __builtin_amdgcn_s_sleep(1);
      }
    }
    __syncthreads();
  }

  if (tid < 256) c_ws[(size_t)gbat * 1024 + hcol] = c_st;   // persist c for next chunk
}

// ---------------- final linear ----------------
__global__ __launch_bounds__(256) void k_final(
    const unsigned int* __restrict__ hp,  // [64][1024] packed h
    const float* __restrict__ wlin,       // [512][1024]
    const float* __restrict__ blin,       // [512]
    float* __restrict__ out)              // [32768] = mu | logvar
{
  __shared__ float hrow[1024];
  int bat = blockIdx.x;
  int tid = threadIdx.x;
  for (int j = tid; j < 1024; j += 256) {
    unsigned int v = hp[(size_t)bat * 1024 + j];
    hrow[j] = bf2f((ushort_t)(v >> 16)) + bf2f((ushort_t)(v & 0xFFFFu));
  }
  __syncthreads();
#pragma unroll
  for (int rep = 0; rep < 2; ++rep) {
    int col = tid + rep * 256;
    const float* wl = wlin + (size_t)col * 1024;
    float sum = 0.f;
    for (int k = 0; k < 1024; k += 4) {
      f32x4 wv = *(const f32x4*)(wl + k);
      sum += hrow[k] * wv[0] + hrow[k + 1] * wv[1] + hrow[k + 2] * wv[2] + hrow[k + 3] * wv[3];
    }
    sum += blin[col];
    if (col < 256) out[(size_t)bat * 256 + col] = sum;
    else           out[16384 + (size_t)bat * 256 + (col - 256)] = sum;
  }
}

// ---------------- launcher ----------------
extern "C" void kernel_launch(void* const* d_in, const int* in_sizes, int n_in,
                              void* d_out, int out_size, void* d_ws, size_t ws_size,
                              hipStream_t stream) {
  const float* x     = (const float*)d_in[0];
  const float* w_ih  = (const float*)d_in[1];
  const float* w_hh  = (const float*)d_in[2];
  const float* b     = (const float*)d_in[3];
  const float* w_lin = (const float*)d_in[4];
  const float* b_lin = (const float*)d_in[5];
  float* out = (float*)d_out;

  char* ws = (char*)d_ws;
  float*    xp       = (float*)ws;                           // 134,217,728
  float*    wihR     = (float*)(ws + 134217728LL);           //   8,388,608
  float*    biasR    = (float*)(ws + 142606336LL);           //      16,384
  ushort_t* whhR_hi  = (ushort_t*)(ws + 142622720LL);        //   8,388,608
  ushort_t* whhR_lo  = (ushort_t*)(ws + 151011328LL);        //   8,388,608
  float*    c_ws     = (float*)(ws + 159399936LL);           //     262,144
  unsigned int* hp0  = (unsigned int*)(ws + 159662080LL);    //     262,144
  unsigned int* arr  = (unsigned int*)(ws + 159924224LL);    //       4,096
  unsigned int* hp1  = (unsigned int*)(ws + 159928320LL);    //     262,144
  // total: 160,190,464 B

  if (ws_size < 160190464ULL) return;  // failure signature: absmax == max|ref| ~ 0.305

  // zero c, packed h buffer 0, barrier counters (contiguous region)
  (void)hipMemsetAsync(ws + 159399936LL, 0, 262144 + 262144 + 4096, stream);

  k_prep<<<1024, 256, 0, stream>>>(w_ih, w_hh, b, wihR, biasR, whhR_hi, whhR_lo);

  for (int c = 0; c < 8; ++c) {
    k_gemm_chunk<<<2048, 256, 0, stream>>>(x, wihR, biasR, xp, c);
    k_lstm_chunk<<<256, 512, 0, stream>>>(xp, whhR_hi, whhR_lo,
                                          hp0, hp1, arr, c_ws, c);
  }
  // each chunk runs 128 steps (even) -> h_final ends in hp0
  k_final<<<64, 256, 0, stream>>>(hp0, w_lin, b_lin, out);
}

// Round 8
// 6423.243 us; speedup vs baseline: 4.4677x; 1.4832x over previous
//
#include <hip/hip_runtime.h>
#include <stdint.h>

typedef __attribute__((ext_vector_type(4))) float f32x4;
typedef __attribute__((ext_vector_type(8))) short s16x8;
typedef __attribute__((ext_vector_type(4))) unsigned int u32x4;
typedef __attribute__((ext_vector_type(2))) unsigned int u32x2;
typedef unsigned short ushort_t;

#define DEVINL static __device__ __forceinline__

DEVINL ushort_t f2bf(float f) {
  unsigned int u = __float_as_uint(f);
  u += 0x7FFFu + ((u >> 16) & 1u);            // RNE
  return (ushort_t)(u >> 16);
}
DEVINL float bf2f(ushort_t h) {
  return __uint_as_float(((unsigned int)h) << 16);
}
DEVINL void split2(float v, ushort_t& hi, ushort_t& lo) {
  hi = f2bf(v);
  lo = f2bf(v - bf2f(hi));                    // combined rel err ~2^-17
}
DEVINL float sigf(float x)   { return 1.f / (1.f + __expf(-x)); }
DEVINL float tanhf_(float x) { return 1.f - 2.f / (__expf(2.f * x) + 1.f); }  // stable both tails

// ---------------- prep: reorder rows into G = hcol*4 + gate; split w_hh ----------------
__global__ __launch_bounds__(256) void k_prep(
    const float* __restrict__ wih,   // [4096][512]  rows: gate*1024 + hcol
    const float* __restrict__ whh,   // [4096][1024]
    const float* __restrict__ b,     // [4096]
    float* __restrict__ wihR,        // [4096][512]  rows: hcol*4 + gate
    float* __restrict__ biasR,       // [4096]
    ushort_t* __restrict__ whhR_hi,  // [4096][1024]
    ushort_t* __restrict__ whhR_lo)
{
  int hcol = blockIdx.x;             // 0..1023
  int tid = threadIdx.x;
  for (int g = 0; g < 4; ++g) {
    int G = hcol * 4 + g;
    int orig = g * 1024 + hcol;
    const float* src_ih = wih + (size_t)orig * 512;
    float* dst_ih = wihR + (size_t)G * 512;
    dst_ih[tid] = src_ih[tid];
    dst_ih[tid + 256] = src_ih[tid + 256];
    const float* src_hh = whh + (size_t)orig * 1024;
    ushort_t* dh = whhR_hi + (size_t)G * 1024;
    ushort_t* dl = whhR_lo + (size_t)G * 1024;
#pragma unroll
    for (int r = 0; r < 4; ++r) {
      int j = tid + r * 256;
      ushort_t h_, l_;
      split2(src_hh[j], h_, l_);
      dh[j] = h_; dl[j] = l_;
    }
    if (tid == 0) biasR[G] = b[orig];
  }
}

// ---------------- xproj split-bf16 GEMM (one T-chunk of 128) ----------------
__global__ __launch_bounds__(256) void k_gemm_chunk(
    const float* __restrict__ x,     // [64][1024][512]
    const float* __restrict__ wihR,  // [4096][512] (G-ordered rows)
    const float* __restrict__ biasR, // [4096]
    float* __restrict__ xp,          // [128][64][4096]
    int chunk)
{
  __shared__ __align__(16) ushort_t Ah[128 * 64], Al[128 * 64];
  __shared__ __align__(16) ushort_t Bh[128 * 64], Bl[128 * 64];
  const int K = 512;
  int bid = blockIdx.x;
  int ntile = bid & 31, mtile = bid >> 5;
  int m0 = mtile * 128, n0 = ntile * 128;
  int tid = threadIdx.x, lane = tid & 63, wv = tid >> 6;
  int wm = wv >> 1, wn = wv & 1;
  int lm = lane & 15, lk = lane >> 4;
  int sr = tid >> 3;
  int sc = (tid & 7) * 8;

  f32x4 acc[4][4] = {};
  float ax[4][8], bx[4][8];

#pragma unroll
  for (int p = 0; p < 4; ++p) {
    int am = m0 + p * 32 + sr;
    const float* ap = x + (size_t)((am >> 7) * 1024 + chunk * 128 + (am & 127)) * K + sc;
    const float* bp = wihR + (size_t)(n0 + p * 32 + sr) * K + sc;
#pragma unroll
    for (int e = 0; e < 8; ++e) ax[p][e] = ap[e];
#pragma unroll
    for (int e = 0; e < 8; ++e) bx[p][e] = bp[e];
  }

  for (int k0 = 0; k0 < K; k0 += 64) {
    __syncthreads();
#pragma unroll
    for (int p = 0; p < 4; ++p) {
      s16x8 vah, val, vbh, vbl;
#pragma unroll
      for (int e = 0; e < 8; ++e) {
        ushort_t h_, l_;
        split2(ax[p][e], h_, l_); vah[e] = (short)h_; val[e] = (short)l_;
        split2(bx[p][e], h_, l_); vbh[e] = (short)h_; vbl[e] = (short)l_;
      }
      int rw = p * 32 + sr;
      int wb = (rw * 128 + sc * 2) ^ ((rw & 7) << 4);
      *(s16x8*)((char*)Ah + wb) = vah;
      *(s16x8*)((char*)Al + wb) = val;
      *(s16x8*)((char*)Bh + wb) = vbh;
      *(s16x8*)((char*)Bl + wb) = vbl;
    }
    __syncthreads();
    if (k0 + 64 < K) {
#pragma unroll
      for (int p = 0; p < 4; ++p) {
        int am = m0 + p * 32 + sr;
        const float* ap = x + (size_t)((am >> 7) * 1024 + chunk * 128 + (am & 127)) * K + (k0 + 64) + sc;
        const float* bp = wihR + (size_t)(n0 + p * 32 + sr) * K + (k0 + 64) + sc;
#pragma unroll
        for (int e = 0; e < 8; ++e) ax[p][e] = ap[e];
#pragma unroll
        for (int e = 0; e < 8; ++e) bx[p][e] = bp[e];
      }
    }
#pragma unroll
    for (int kk = 0; kk < 2; ++kk) {
      s16x8 fah[4], fal[4], fbh[4], fbl[4];
      int cb = (kk * 32 + lk * 8) * 2;
#pragma unroll
      for (int i = 0; i < 4; ++i) {
        int rA = wm * 64 + i * 16 + lm;
        int rB = wn * 64 + i * 16 + lm;
        int oa = (rA * 128 + cb) ^ ((rA & 7) << 4);
        int ob = (rB * 128 + cb) ^ ((rB & 7) << 4);
        fah[i] = *(const s16x8*)((const char*)Ah + oa);
        fal[i] = *(const s16x8*)((const char*)Al + oa);
        fbh[i] = *(const s16x8*)((const char*)Bh + ob);
        fbl[i] = *(const s16x8*)((const char*)Bl + ob);
      }
#pragma unroll
      for (int i = 0; i < 4; ++i)
#pragma unroll
        for (int j = 0; j < 4; ++j) {
          acc[i][j] = __builtin_amdgcn_mfma_f32_16x16x32_bf16(fah[i], fbh[j], acc[i][j], 0, 0, 0);
          acc[i][j] = __builtin_amdgcn_mfma_f32_16x16x32_bf16(fah[i], fbl[j], acc[i][j], 0, 0, 0);
          acc[i][j] = __builtin_amdgcn_mfma_f32_16x16x32_bf16(fal[i], fbh[j], acc[i][j], 0, 0, 0);
        }
    }
  }
#pragma unroll
  for (int j = 0; j < 4; ++j) {
    int G = n0 + wn * 64 + j * 16 + lm;
    float bv = biasR[G];
#pragma unroll
    for (int i = 0; i < 4; ++i) {
      int mb = m0 + wm * 64 + i * 16 + lk * 4;
#pragma unroll
      for (int r = 0; r < 4; ++r) {
        int m = mb + r;
        xp[((size_t)(m & 127) * 64 + (m >> 7)) * 4096 + G] = acc[i][j][r] + bv;
      }
    }
  }
}

// ---------------- persistent LSTM recurrence, one T-chunk of 128 steps ----------------
// 256 WGs x 512 thr (grid <= #CUs: co-residency guaranteed). Group g = bid>>6 owns batches
// [16g,16g+16); WG w = bid&63 owns hcols [16w,16w+16). h exchanged packed u32 (hi<<16|lo)
// via LLC-bypass accesses. Per-wave JIT poll+restage: wave j waits only its 8 producers,
// then loads their col-slices [128j,128j+128) with 16B bypass loads. Weights pinned in VGPRs.
__global__ __launch_bounds__(512, 1) void k_lstm_chunk(
    const float* __restrict__ xp,          // [128][64][4096]
    const ushort_t* __restrict__ whh_hi,   // [4096][1024]
    const ushort_t* __restrict__ whh_lo,
    unsigned int* __restrict__ hp0,        // [4][16][1024] packed h (hi<<16|lo)
    unsigned int* __restrict__ hp1,
    unsigned int* __restrict__ arrived,    // [4][64]
    float* __restrict__ c_ws,              // [64][1024]
    int chunk)
{
  __shared__ __align__(16) ushort_t hA[16 * 1024];   // hi plane, swizzled
  __shared__ __align__(16) ushort_t hB[16 * 1024];   // lo plane, swizzled
  __shared__ float g0[4][16][17], g1[4][16][17];

  int bid = blockIdx.x;
  int g = bid >> 6, w = bid & 63;
  int tid = threadIdx.x, lane = tid & 63, wid = tid >> 6;
  int kh = wid & 1, cg = wid >> 1;
  int lm = lane & 15, lk = lane >> 4;

  // --- this wave's w_hh hi/lo B-frags, loaded once and PINNED in registers ---
  s16x8 bh[16], bl[16];
  {
    int gcol = w * 64 + cg * 16 + lm;
    const ushort_t* ph = whh_hi + (size_t)gcol * 1024 + kh * 512 + lk * 8;
    const ushort_t* pl = whh_lo + (size_t)gcol * 1024 + kh * 512 + lk * 8;
#pragma unroll
    for (int kk = 0; kk < 16; ++kk) {
      bh[kk] = *(const s16x8*)(ph + kk * 32);
      bl[kk] = *(const s16x8*)(pl + kk * 32);
    }
  }
#pragma unroll
  for (int kk = 0; kk < 16; ++kk)
    asm volatile("" : "+v"(bh[kk]), "+v"(bl[kk]));   // defeat rematerialization

  // cell ownership (tid < 256): bat = tid>>4, hc = tid&15
  int bat = tid >> 4, hc = tid & 15;
  int gbat = g * 16 + bat;
  int hcol = w * 16 + hc;
  float c_st = (tid < 256) ? c_ws[(size_t)gbat * 1024 + hcol] : 0.f;

  unsigned int* grp = arrived + g * 64;
  unsigned int* hp0g = hp0 + g * 16384;
  unsigned int* hp1g = hp1 + g * 16384;

  // restage constants: wave wid covers cols [128*wid, 128*wid+128)
  int rl_bat0 = lane >> 4;          // 0..3
  int rl_colo = (lane & 15) * 4;    // 0..60
  int colbase = 128 * wid;

  f32x4 xv_cur = {};
  if (tid < 256)
    xv_cur = *(const f32x4*)(xp + (size_t)gbat * 4096 + w * 64 + hc * 4);

  for (int tl = 0; tl < 128; ++tl) {
    const unsigned int* sp = (tl & 1) ? hp1g : hp0g;
    unsigned int* dp = (tl & 1) ? hp0g : hp1g;

    // --- per-wave JIT: poll my 8 producers, then bypass-load their slices ---
    {
      unsigned int tgt = (unsigned int)(chunk * 128 + tl);
      int spin = 0;
      while (1) {
        unsigned int v = tgt;
        if (lane < 8)
          v = __hip_atomic_load(grp + wid * 8 + lane, __ATOMIC_RELAXED, __HIP_MEMORY_SCOPE_AGENT);
        if (__all((int)(v >= tgt))) break;
        if (++spin > (1 << 16)) break;            // bailout: wrong answer, never a hang
        __builtin_amdgcn_s_sleep(1);
      }
    }
    u32x4 r[8];
#pragma unroll
    for (int i = 0; i < 8; ++i) {
      int bi = rl_bat0 + 4 * (i & 3);
      int ci = colbase + rl_colo + 64 * (i >> 2);
      const unsigned int* sa = sp + bi * 1024 + ci;
      asm volatile("global_load_dwordx4 %0, %1, off sc0 sc1"
                   : "=v"(r[i]) : "v"(sa) : "memory");
    }
    asm volatile("s_waitcnt vmcnt(0)" ::: "memory");
    __builtin_amdgcn_sched_barrier(0);
#pragma unroll
    for (int i = 0; i < 8; ++i) {
      int bi = rl_bat0 + 4 * (i & 3);
      int ci = colbase + rl_colo + 64 * (i >> 2);
      unsigned int hi01 = __builtin_amdgcn_perm(r[i][1], r[i][0], 0x07060302u);
      unsigned int hi23 = __builtin_amdgcn_perm(r[i][3], r[i][2], 0x07060302u);
      unsigned int lo01 = __builtin_amdgcn_perm(r[i][1], r[i][0], 0x05040100u);
      unsigned int lo23 = __builtin_amdgcn_perm(r[i][3], r[i][2], 0x05040100u);
      int d = (bi * 2048 + ci * 2) ^ ((bi & 7) << 4);
      u32x2 vh = { hi01, hi23 };
      u32x2 vl = { lo01, lo23 };
      *(u32x2*)((char*)hA + d) = vh;
      *(u32x2*)((char*)hB + d) = vl;
    }
    __syncthreads();

    // prefetch next step's xp (consumed next iteration -> HBM latency off critical path)
    f32x4 xv_next = xv_cur;
    {
      int tln = (tl + 1 < 128) ? (tl + 1) : tl;
      if (tid < 256)
        xv_next = *(const f32x4*)(xp + ((size_t)tln * 64 + gbat) * 4096 + w * 64 + hc * 4);
    }

    // --- split GEMM, this wave: 16 bats x its 16 G-cols, K-half kh ---
    f32x4 acc = {};
#pragma unroll
    for (int kk = 0; kk < 16; ++kk) {
      int kb = (kh * 512 + kk * 32 + lk * 8) * 2;
      int off = (lm * 2048 + kb) ^ ((lm & 7) << 4);
      s16x8 ah = *(const s16x8*)((const char*)hA + off);
      s16x8 al = *(const s16x8*)((const char*)hB + off);
      acc = __builtin_amdgcn_mfma_f32_16x16x32_bf16(ah, bh[kk], acc, 0, 0, 0);
      acc = __builtin_amdgcn_mfma_f32_16x16x32_bf16(al, bh[kk], acc, 0, 0, 0);
      acc = __builtin_amdgcn_mfma_f32_16x16x32_bf16(ah, bl[kk], acc, 0, 0, 0);
    }
    {
      float (*gp)[16][17] = kh ? g1 : g0;
#pragma unroll
      for (int r_ = 0; r_ < 4; ++r_)
        gp[cg][lk * 4 + r_][lm] = acc[r_];
    }
    __syncthreads();

    // --- elementwise cell update; publish h via bypass store ---
    if (tid < 256) {
      int cgi = hc >> 2, nb = (hc & 3) * 4;
      float gi = g0[cgi][bat][nb + 0] + g1[cgi][bat][nb + 0] + xv_cur[0];
      float gf = g0[cgi][bat][nb + 1] + g1[cgi][bat][nb + 1] + xv_cur[1];
      float gg = g0[cgi][bat][nb + 2] + g1[cgi][bat][nb + 2] + xv_cur[2];
      float go = g0[cgi][bat][nb + 3] + g1[cgi][bat][nb + 3] + xv_cur[3];
      float iv = sigf(gi), fv = sigf(gf), gv = tanhf_(gg), ov = sigf(go);
      c_st = fv * c_st + iv * gv;
      float hv = ov * tanhf_(c_st);
      ushort_t h_, l_;
      split2(hv, h_, l_);
      unsigned int pk = ((unsigned int)h_ << 16) | (unsigned int)l_;
      __hip_atomic_store(dp + bat * 1024 + hcol, pk,
                         __ATOMIC_RELAXED, __HIP_MEMORY_SCOPE_AGENT);
    }

    // arrival: syncthreads drains each wave's stores, then one flag store
    __syncthreads();
    if (tid == 0)
      __hip_atomic_store(grp + w, (unsigned int)(chunk * 128 + tl + 1),
                         __ATOMIC_RELAXED, __HIP_MEMORY_SCOPE_AGENT);
    xv_cur = xv_next;
  }

  if (tid < 256) c_ws[(size_t)gbat * 1024 + hcol] = c_st;   // persist c for next chunk
}

// ---------------- final linear ----------------
__global__ __launch_bounds__(256) void k_final(
    const unsigned int* __restrict__ hp,  // [64][1024] packed h
    const float* __restrict__ wlin,       // [512][1024]
    const float* __restrict__ blin,       // [512]
    float* __restrict__ out)              // [32768] = mu | logvar
{
  __shared__ float hrow[1024];
  int bat = blockIdx.x;
  int tid = threadIdx.x;
  for (int j = tid; j < 1024; j += 256) {
    unsigned int v = hp[(size_t)bat * 1024 + j];
    hrow[j] = bf2f((ushort_t)(v >> 16)) + bf2f((ushort_t)(v & 0xFFFFu));
  }
  __syncthreads();
#pragma unroll
  for (int rep = 0; rep < 2; ++rep) {
    int col = tid + rep * 256;
    const float* wl = wlin + (size_t)col * 1024;
    float sum = 0.f;
    for (int k = 0; k < 1024; k += 4) {
      f32x4 wv = *(const f32x4*)(wl + k);
      sum += hrow[k] * wv[0] + hrow[k + 1] * wv[1] + hrow[k + 2] * wv[2] + hrow[k + 3] * wv[3];
    }
    sum += blin[col];
    if (col < 256) out[(size_t)bat * 256 + col] = sum;
    else           out[16384 + (size_t)bat * 256 + (col - 256)] = sum;
  }
}

// ---------------- launcher ----------------
extern "C" void kernel_launch(void* const* d_in, const int* in_sizes, int n_in,
                              void* d_out, int out_size, void* d_ws, size_t ws_size,
                              hipStream_t stream) {
  const float* x     = (const float*)d_in[0];
  const float* w_ih  = (const float*)d_in[1];
  const float* w_hh  = (const float*)d_in[2];
  const float* b     = (const float*)d_in[3];
  const float* w_lin = (const float*)d_in[4];
  const float* b_lin = (const float*)d_in[5];
  float* out = (float*)d_out;

  char* ws = (char*)d_ws;
  float*    xp       = (float*)ws;                           // 134,217,728
  float*    wihR     = (float*)(ws + 134217728LL);           //   8,388,608
  float*    biasR    = (float*)(ws + 142606336LL);           //      16,384
  ushort_t* whhR_hi  = (ushort_t*)(ws + 142622720LL);        //   8,388,608
  ushort_t* whhR_lo  = (ushort_t*)(ws + 151011328LL);        //   8,388,608
  float*    c_ws     = (float*)(ws + 159399936LL);           //     262,144
  unsigned int* hp0  = (unsigned int*)(ws + 159662080LL);    //     262,144
  unsigned int* arr  = (unsigned int*)(ws + 159924224LL);    //       4,096
  unsigned int* hp1  = (unsigned int*)(ws + 159928320LL);    //     262,144
  // total: 160,190,464 B

  if (ws_size < 160190464ULL) return;  // failure signature: absmax == max|ref| ~ 0.305

  // zero c, packed h buffer 0, barrier counters (contiguous region)
  (void)hipMemsetAsync(ws + 159399936LL, 0, 262144 + 262144 + 4096, stream);

  k_prep<<<1024, 256, 0, stream>>>(w_ih, w_hh, b, wihR, biasR, whhR_hi, whhR_lo);

  for (int c = 0; c < 8; ++c) {
    k_gemm_chunk<<<2048, 256, 0, stream>>>(x, wihR, biasR, xp, c);
    k_lstm_chunk<<<256, 512, 0, stream>>>(xp, whhR_hi, whhR_lo,
                                          hp0, hp1, arr, c_ws, c);
  }
  // each chunk runs 128 steps (even) -> h_final ends in hp0
  k_final<<<64, 256, 0, stream>>>(hp0, w_lin, b_lin, out);
}